// Round 8
// baseline (11473.945 us; speedup 1.0000x reference)
//
#include <hip/hip_runtime.h>
#include <hip/hip_bf16.h>

typedef short short8 __attribute__((ext_vector_type(8)));
typedef float floatx4 __attribute__((ext_vector_type(4)));
typedef _Float16 h2v __attribute__((ext_vector_type(2)));

#define B_ 64
#define L_ 196
#define T_ 31
#define PRED_ 19840000ULL

__device__ __forceinline__ float bf2f(unsigned short u){
  union { unsigned int i; float f; } v; v.i = ((unsigned int)u)<<16; return v.f;
}
__device__ __forceinline__ unsigned short bfu(float x){
  union { __hip_bfloat16 h; unsigned short u; } v; v.h = __float2bfloat16(x); return v.u;
}
__device__ __forceinline__ unsigned int pk2(float a, float b){
  return (unsigned int)bfu(a) | ((unsigned int)bfu(b) << 16);
}
__device__ __forceinline__ unsigned int pkh2(float a, float b){
  union { _Float16 h[2]; unsigned int u; } v;
  v.h[0] = (_Float16)a; v.h[1] = (_Float16)b; return v.u;
}
__device__ __forceinline__ float sigm(float x){ return 1.0f/(1.0f+__expf(-x)); }

// packed f16-pair dot product: c += a.lo*b.lo + a.hi*b.hi
__device__ __forceinline__ float dot2(unsigned int a, unsigned int b, float c){
#if __has_builtin(__builtin_amdgcn_fdot2)
  return __builtin_amdgcn_fdot2(__builtin_bit_cast(h2v, a), __builtin_bit_cast(h2v, b), c, false);
#else
  union { unsigned int u; _Float16 h[2]; } x, y; x.u = a; y.u = b;
  return c + (float)x.h[0]*(float)y.h[0] + (float)x.h[1]*(float)y.h[1];
#endif
}

// ---------------- cast f32 -> bf16 (vector x4) ----------------
__global__ __launch_bounds__(256) void k_cast(const float* __restrict__ src,
                                              __hip_bfloat16* __restrict__ dst, int n4){
  int i = blockIdx.x*256 + threadIdx.x;
  if (i < n4){
    const float4 v = *(const float4*)(src + (size_t)i*4);
    size_t o = (size_t)i*4;
    dst[o+0] = __float2bfloat16(v.x);
    dst[o+1] = __float2bfloat16(v.y);
    dst[o+2] = __float2bfloat16(v.z);
    dst[o+3] = __float2bfloat16(v.w);
  }
}

// ------- tiled transpose: src (Kin x Nin) -> dst[n][k] bf16, row stride S --------
__global__ __launch_bounds__(1024) void k_trans_bf16(const float* __restrict__ src,
    __hip_bfloat16* __restrict__ dst, int Kin, int Nin, int S, int Rtot){
  __shared__ float tile[32][33];
  int n0 = blockIdx.x*32, k0 = blockIdx.y*32;
  int x = threadIdx.x & 31, y = threadIdx.x >> 5;
  int k = k0 + y, nn = n0 + x;
  tile[y][x] = (k < Kin && nn < Nin) ? src[(size_t)k*Nin + nn] : 0.0f;
  __syncthreads();
  int n2 = n0 + y, k2 = k0 + x;
  if (n2 < Rtot && k2 < Kin) dst[(size_t)n2*S + k2] = __float2bfloat16(tile[x][y]);
}

// ---- pack k-pairs (no transpose): W1p[kp][n] u32 = (W[2kp][n], W[2kp+1][n]) f16x2 ----
// n<512: W_da ; 512<=n<1024: W_fb ; n>=1024: W_hh
__global__ __launch_bounds__(1024) void k_pack1(const float* __restrict__ Wda,
    const float* __restrict__ Wfb, const float* __restrict__ Whh,
    unsigned int* __restrict__ W1p){
  int kp = blockIdx.y; int n = blockIdx.x*1024 + threadIdx.x;   // grid(3,256)
  float v0, v1;
  if (n < 512){       v0 = Wda[(size_t)(2*kp)*512 + n];        v1 = Wda[(size_t)(2*kp+1)*512 + n]; }
  else if (n < 1024){ v0 = Wfb[(size_t)(2*kp)*512 + n-512];    v1 = Wfb[(size_t)(2*kp+1)*512 + n-512]; }
  else {              v0 = Whh[(size_t)(2*kp)*2048 + n-1024];  v1 = Whh[(size_t)(2*kp+1)*2048 + n-1024]; }
  W1p[(size_t)kp*3072 + n] = pkh2(v0, v1);
}

// W2p[kp][n] from W_ih rows 512..1023 (the z-half)
__global__ __launch_bounds__(1024) void k_pack2(const float* __restrict__ Wih,
    unsigned int* __restrict__ W2p){
  int kp = blockIdx.y; int n = blockIdx.x*1024 + threadIdx.x;   // grid(2,256)
  float v0 = Wih[(size_t)(512 + 2*kp)*2048 + n];
  float v1 = Wih[(size_t)(513 + 2*kp)*2048 + n];
  W2p[(size_t)kp*2048 + n] = pkh2(v0, v1);
}

// ---------------- embedding gather: Erow[(t*64+b)][m] bf16 -------
__global__ __launch_bounds__(512) void k_emb(const int* __restrict__ captions,
    const float* __restrict__ emb, __hip_bfloat16* __restrict__ Erow){
  int tb = blockIdx.x; int t = tb >> 6; int b = tb & 63; int m = threadIdx.x;
  int cap = captions[b*32 + t];
  Erow[((size_t)(t*64 + b))*512 + m] = __float2bfloat16(emb[(size_t)cap*512 + m]);
}

// ---------------- init h0/c0 (one block per b), row-major [b][512] ----------------
__global__ __launch_bounds__(512) void k_init(const float* __restrict__ enc,
    const float* __restrict__ Whi, const float* __restrict__ bhi,
    const float* __restrict__ Wci, const float* __restrict__ bci,
    float* __restrict__ hb0, float* __restrict__ cb0){
  int b = blockIdx.x; int d = threadIdx.x;
  __shared__ float ms[512];
  const float* eb = enc + (size_t)b*L_*512;
  float s = 0.f;
  for (int l = 0; l < L_; l++) s += eb[(size_t)l*512 + d];
  ms[d] = s * (1.0f/196.0f);
  __syncthreads();
  float a1 = bhi[d], a2 = bci[d];
  #pragma unroll 4
  for (int k = 0; k < 512; k++){
    float mv = ms[k];
    a1 += mv * Whi[(size_t)k*512 + d];
    a2 += mv * Wci[(size_t)k*512 + d];
  }
  hb0[(size_t)b*512 + d] = tanhf(a1);
  cb0[(size_t)b*512 + d] = tanhf(a2);
}

// ---------------- MFMA bf16 GEMM: C(64x64 tiles) = A(MxK) @ Bt(NxK)^T ----------------
// mode 0: att1R  -> outB bf16 row-major [r][c] = acc + bias1[c]
// mode 1: U      -> outB bf16 = acc + bias1[c] + bias2[c] + Erow[r][c]
// mode 2: logits -> outF f32  = mask(t<dec_len)*(acc+bias1[c]) at [b][t][c]; 1-D swizzled grid
// mode 3: preIHb -> outB bf16 at [b][t][c] (r -> t=r>>6, b=r&63)
__global__ __launch_bounds__(256) void k_gemm(const __hip_bfloat16* __restrict__ Abf,
    const __hip_bfloat16* __restrict__ Bt, int K, int mode, int Nreal,
    const float* __restrict__ bias1, const float* __restrict__ bias2,
    const __hip_bfloat16* __restrict__ Erow, const int* __restrict__ caplen,
    __hip_bfloat16* __restrict__ outB, float* __restrict__ outF){
  int bx = blockIdx.x, by = blockIdx.y;
  if (mode == 2){
    // bijective XCD-chunk swizzle over 4867 = 157*31 tiles (q=608, r=3)
    int i = bx; int xcd = i & 7; int ii = i >> 3;
    int s = (xcd < 3) ? xcd*609 + ii : 3*609 + (xcd-3)*608 + ii;
    by = s % 31;      // mb
    bx = s / 31;      // nb
  }
  int lane = threadIdx.x & 63; int wv = threadIdx.x >> 6;
  int wr = wv >> 1, wc = wv & 1;
  int r0 = by*64 + wr*32;
  int c0 = bx*64 + wc*32;
  int l15 = lane & 15, lg = lane >> 4;
  const short* Ap = (const short*)Abf;
  const short* Bp = (const short*)Bt;
  floatx4 acc00 = {0,0,0,0}, acc01 = {0,0,0,0}, acc10 = {0,0,0,0}, acc11 = {0,0,0,0};
  size_t ar0 = (size_t)(r0 + l15)*K + lg*8;
  size_t ar1 = ar0 + (size_t)16*K;
  size_t br0 = (size_t)(c0 + l15)*K + lg*8;
  size_t br1 = br0 + (size_t)16*K;
  #pragma unroll 4
  for (int k0 = 0; k0 < K; k0 += 32){
    short8 av0 = *(const short8*)(Ap + ar0 + k0);
    short8 av1 = *(const short8*)(Ap + ar1 + k0);
    short8 bv0 = *(const short8*)(Bp + br0 + k0);
    short8 bv1 = *(const short8*)(Bp + br1 + k0);
    acc00 = __builtin_amdgcn_mfma_f32_16x16x32_bf16(av0, bv0, acc00, 0, 0, 0);
    acc01 = __builtin_amdgcn_mfma_f32_16x16x32_bf16(av0, bv1, acc01, 0, 0, 0);
    acc10 = __builtin_amdgcn_mfma_f32_16x16x32_bf16(av1, bv0, acc10, 0, 0, 0);
    acc11 = __builtin_amdgcn_mfma_f32_16x16x32_bf16(av1, bv1, acc11, 0, 0, 0);
  }
  floatx4 accs[2][2] = {{acc00, acc01}, {acc10, acc11}};
  #pragma unroll
  for (int i = 0; i < 2; i++){
    #pragma unroll
    for (int j = 0; j < 2; j++){
      #pragma unroll
      for (int v = 0; v < 4; v++){
        int r = r0 + 16*i + lg*4 + v;
        int c = c0 + 16*j + l15;
        float val = accs[i][j][v];
        if (mode == 0){
          outB[(size_t)r*512 + c] = __float2bfloat16(val + bias1[c]);
        } else if (mode == 1){
          float e = bf2f(((const unsigned short*)Erow)[(size_t)r*512 + c]);
          outB[(size_t)r*512 + c] = __float2bfloat16(val + bias1[c] + bias2[c] + e);
        } else if (mode == 2){
          if (c < Nreal){
            int t = r >> 6, b = r & 63;
            float mf = (t < caplen[b] - 1) ? 1.f : 0.f;
            outF[((size_t)b*T_ + t)*10000 + c] = (val + bias1[c]) * mf;
          }
        } else {
          outB[((size_t)(r & 63)*T_ + (r >> 6))*2048 + c] = __float2bfloat16(val);
        }
      }
    }
  }
}

// ============ the full 31-step recurrence: one block per batch, NO grid syncs ============
// 64 blocks x 1024 threads. All state (h,c) lives in LDS for all 31 steps.
// Weights streamed per step, k-pair packed u32 [kp][n] (coalesced), consumed via fdot2.
__global__ __launch_bounds__(1024) void k_loop(
    const unsigned int* __restrict__ W1p,     // [256][3072] u32: att2(512)|beta(512)|whh(2048)
    const unsigned int* __restrict__ W2p,     // [256][2048] u32: W_ih z-half
    const __hip_bfloat16* __restrict__ preIHb,// [64][31][2048]
    const __hip_bfloat16* __restrict__ att1R, // [64*196][512]
    const __hip_bfloat16* __restrict__ enc_bf,// [64][196][512]
    const float* __restrict__ wfa,
    const float* __restrict__ b_da, const float* __restrict__ b_fb,
    const float* __restrict__ b_ih, const float* __restrict__ b_hh,
    const float* __restrict__ hb0, const float* __restrict__ cb0,  // [64][512]
    __hip_bfloat16* __restrict__ HZ,          // [1984][1024]
    const int* __restrict__ caplen,
    float* __restrict__ outAlpha)
{
  int tid = threadIdx.x, lane = tid & 63, w = tid >> 6;   // w in [0,16)
  int b = blockIdx.x;

  __shared__ unsigned int hpk[256];   // h as f16 pairs
  __shared__ unsigned int zpk[256];   // z as f16 pairs
  __shared__ float hs[512], cs[512];
  __shared__ float att2s[512], betas[512];
  __shared__ float es[196], ps[196];
  __shared__ float zsc[512];
  __shared__ float gfo[2][512];
  __shared__ float wfa_l[512];
  __shared__ float MS[1];

  // ---- staging ----
  if (tid < 512){
    hs[tid] = hb0[(size_t)b*512 + tid];
    cs[tid] = cb0[(size_t)b*512 + tid];
    wfa_l[tid] = wfa[tid];
  }
  __syncthreads();
  if (tid < 256) hpk[tid] = pkh2(hs[2*tid], hs[2*tid+1]);
  float biasA = (tid < 512) ? b_da[tid] : b_fb[tid - 512];
  float bs0 = b_ih[tid]        + b_hh[tid];
  float bs1 = b_ih[1024 + tid] + b_hh[1024 + tid];
  int dl = caplen[b] - 1;
  __syncthreads();

  for (int t = 0; t < T_; t++){
    // ===== M1: h @ [W_da | W_fb | W_hh] — thread owns n = {tid, 1024+tid, 2048+tid} =====
    float a0 = 0.f, a1 = 0.f, a2 = 0.f;
    {
      const unsigned int* wp = W1p + tid;
      #pragma unroll 4
      for (int kp = 0; kp < 256; kp++){
        unsigned int hh = hpk[kp];
        a0 = dot2(wp[0],    hh, a0);
        a1 = dot2(wp[1024], hh, a1);
        a2 = dot2(wp[2048], hh, a2);
        wp += 3072;
      }
    }
    if (tid < 512) att2s[tid] = a0 + biasA;
    else           betas[tid - 512] = a0 + biasA;
    // a1 = whh part of gate n=tid (i|f), a2 = gate n=1024+tid (g|o) — stay in regs
    if (tid < 512) zsc[tid] = 0.f;
    __syncthreads();

    // ===== e-pass: e[l] = sum_a relu(att1[l][a] + att2[a]) * wfa[a] =====
    {
      float a2r[8], wfr[8];
      #pragma unroll
      for (int u = 0; u < 8; u++){ a2r[u] = att2s[lane*8+u]; wfr[u] = wfa_l[lane*8+u]; }
      #pragma unroll
      for (int i = 0; i < 13; i++){
        int l = w + i*16;
        if (l < 196){
          short8 av = *(const short8*)((const short*)att1R + ((size_t)(b*196 + l))*512 + lane*8);
          float e = 0.f;
          #pragma unroll
          for (int u = 0; u < 8; u++){
            float v = bf2f((unsigned short)av[u]) + a2r[u];
            e += fmaxf(v, 0.f) * wfr[u];
          }
          #pragma unroll
          for (int off = 32; off; off >>= 1) e += __shfl_xor(e, off, 64);
          if (lane == 0) es[l] = e;
        }
      }
    }
    __syncthreads();

    // ===== softmax over 196 (wave 0) =====
    if (w == 0){
      float v0 = es[lane], v1 = es[lane+64], v2 = es[lane+128];
      float v3 = (lane < 4) ? es[lane+192] : -3e38f;
      float m = fmaxf(fmaxf(v0,v1), fmaxf(v2,v3));
      #pragma unroll
      for (int off = 32; off; off >>= 1) m = fmaxf(m, __shfl_xor(m, off, 64));
      float p0 = __expf(v0-m), p1 = __expf(v1-m), p2 = __expf(v2-m);
      float p3 = (lane < 4) ? __expf(v3-m) : 0.f;
      float s = p0+p1+p2+p3;
      #pragma unroll
      for (int off = 32; off; off >>= 1) s += __shfl_xor(s, off, 64);
      ps[lane] = p0; ps[lane+64] = p1; ps[lane+128] = p2;
      if (lane < 4) ps[lane+192] = p3;
      if (lane == 0) MS[0] = 1.f / s;
    }
    __syncthreads();
    float inv = MS[0];
    if (tid < 196){
      float mf = (t < dl) ? 1.f : 0.f;
      outAlpha[((size_t)b*T_ + t)*196 + tid] = ps[tid] * inv * mf;
    }

    // ===== z-pass: z[d] = sum_l p[l] * enc[l][d] =====
    {
      float zac[8] = {0,0,0,0,0,0,0,0};
      #pragma unroll
      for (int i = 0; i < 13; i++){
        int l = w + i*16; int lc = (l < 196) ? l : 195;
        short8 ev = *(const short8*)((const short*)enc_bf + ((size_t)(b*196 + lc))*512 + lane*8);
        float pl = (l < 196) ? ps[l] : 0.f;
        #pragma unroll
        for (int u = 0; u < 8; u++) zac[u] += pl * bf2f((unsigned short)ev[u]);
      }
      #pragma unroll
      for (int u = 0; u < 8; u++) atomicAdd(&zsc[lane*8 + u], zac[u]);
    }
    __syncthreads();

    // ===== z combine: beta-gate, pack, write HZ z-half =====
    if (tid < 256){
      int d0 = tid*2;
      float za = zsc[d0]   * inv * sigm(betas[d0]);
      float zb = zsc[d0+1] * inv * sigm(betas[d0+1]);
      zpk[tid] = pkh2(za, zb);
      *(unsigned int*)((unsigned short*)HZ + ((size_t)(t*64 + b))*1024 + 512 + d0) = pk2(za, zb);
    }
    __syncthreads();

    // ===== M2: z @ W_ihz — thread owns gate n = {tid, 1024+tid} =====
    float g0 = a1 + bs0;
    float g1 = a2 + bs1;
    {
      const unsigned int* wp = W2p + tid;
      #pragma unroll 4
      for (int kp = 0; kp < 256; kp++){
        unsigned int zz = zpk[kp];
        g0 = dot2(wp[0],    zz, g0);
        g1 = dot2(wp[1024], zz, g1);
        wp += 2048;
      }
    }
    {
      const unsigned short* pre = (const unsigned short*)preIHb + ((size_t)b*T_ + t)*2048;
      g0 += bf2f(pre[tid]);
      g1 += bf2f(pre[1024 + tid]);
    }
    // threads >=512 hold (f,o) for dim tid-512 — exchange via LDS
    if (tid >= 512){ gfo[0][tid-512] = g0; gfo[1][tid-512] = g1; }
    __syncthreads();

    // ===== LSTM pointwise + state update (threads 0..511 own dim d=tid) =====
    if (tid < 512){
      float gi = g0, gg = g1;
      float gf = gfo[0][tid], go = gfo[1][tid];
      float c_old = cs[tid];
      float c_new = sigm(gf)*c_old + sigm(gi)*tanhf(gg);
      float h_new = sigm(go)*tanhf(c_new);
      bool mm = (t < dl);
      float hm = mm ? h_new : hs[tid];
      cs[tid] = mm ? c_new : c_old;
      hs[tid] = hm;
      ((unsigned short*)HZ)[((size_t)(t*64 + b))*1024 + tid] = bfu(h_new);  // unmasked
    }
    __syncthreads();
    if (tid < 256) hpk[tid] = pkh2(hs[2*tid], hs[2*tid+1]);
    __syncthreads();
  }
}

extern "C" void kernel_launch(void* const* d_in, const int* in_sizes, int n_in,
                              void* d_out, int out_size, void* d_ws, size_t ws_size,
                              hipStream_t stream){
  (void)in_sizes; (void)n_in; (void)out_size; (void)ws_size;
  const float* enc    = (const float*)d_in[0];
  const int* captions = (const int*)d_in[1];
  const int* caplen   = (const int*)d_in[2];
  const float* emb    = (const float*)d_in[3];
  const float* W_ea  = (const float*)d_in[4];  const float* b_ea = (const float*)d_in[5];
  const float* W_da  = (const float*)d_in[6];  const float* b_da = (const float*)d_in[7];
  const float* w_fa  = (const float*)d_in[8];  /* b_fa cancels in softmax */
  const float* W_hi  = (const float*)d_in[10]; const float* b_hi = (const float*)d_in[11];
  const float* W_ci  = (const float*)d_in[12]; const float* b_ci = (const float*)d_in[13];
  const float* W_ih  = (const float*)d_in[14]; const float* W_hh = (const float*)d_in[15];
  const float* b_ih  = (const float*)d_in[16]; const float* b_hh = (const float*)d_in[17];
  const float* W_fb  = (const float*)d_in[18]; const float* b_fb = (const float*)d_in[19];
  const float* W_lh  = (const float*)d_in[20]; const float* b_lh = (const float*)d_in[21];
  const float* W_lz  = (const float*)d_in[22]; const float* b_lz = (const float*)d_in[23];
  const float* W_lo  = (const float*)d_in[24]; const float* b_lo = (const float*)d_in[25];
  float* out = (float*)d_out;

  char* p = (char*)d_ws;
  auto alloc = [&](size_t bytes){ char* r = p; p += (bytes + 255) & ~(size_t)255; return r; };
  __hip_bfloat16* enc_bf = (__hip_bfloat16*)alloc(12845056); // 64*196*512
  __hip_bfloat16* att1R  = (__hip_bfloat16*)alloc(12845056); // [64*196][512]
  __hip_bfloat16* WeaT   = (__hip_bfloat16*)alloc(524288);   // 512x512
  unsigned int*   W1p    = (unsigned int*)alloc(3145728);    // 256x3072 u32
  unsigned int*   W2p    = (unsigned int*)alloc(2097152);    // 256x2048 u32
  __hip_bfloat16* WtopT  = (__hip_bfloat16*)alloc(2097152);  // 2048x512
  __hip_bfloat16* W2T    = (__hip_bfloat16*)alloc(1048576);  // 512x1024
  __hip_bfloat16* WloT   = (__hip_bfloat16*)alloc(10289152); // 10048x512
  __hip_bfloat16* Erow   = (__hip_bfloat16*)alloc(2031616);  // 1984x512
  __hip_bfloat16* preIHb = (__hip_bfloat16*)alloc(8126464);  // 64x31x2048
  __hip_bfloat16* HZ     = (__hip_bfloat16*)alloc(4063232);  // 1984x1024
  __hip_bfloat16* Ubf    = (__hip_bfloat16*)alloc(2031616);  // 1984x512
  float*        hb0    = (float*)alloc(131072);              // 64x512
  float*        cb0    = (float*)alloc(131072);

  // ---- setup: casts / packs / transposes / embedding / init ----
  k_cast<<<dim3(6272), dim3(256), 0, stream>>>(enc, enc_bf, 1605632);
  k_pack1<<<dim3(3, 256), dim3(1024), 0, stream>>>(W_da, W_fb, W_hh, W1p);
  k_pack2<<<dim3(2, 256), dim3(1024), 0, stream>>>(W_ih, W2p);
  k_trans_bf16<<<dim3(16, 16), dim3(1024), 0, stream>>>(W_ea, WeaT,      512, 512,   512,  512);
  k_trans_bf16<<<dim3(64, 16), dim3(1024), 0, stream>>>(W_ih, WtopT,     512, 2048,  512,  2048);
  k_trans_bf16<<<dim3(16, 16), dim3(1024), 0, stream>>>(W_lh, W2T,       512, 512,   1024, 512);
  k_trans_bf16<<<dim3(16, 16), dim3(1024), 0, stream>>>(W_lz, W2T + 512, 512, 512,   1024, 512);
  k_trans_bf16<<<dim3(314, 16), dim3(1024), 0, stream>>>(W_lo, WloT,     512, 10000, 512,  10048);
  k_emb<<<dim3(1984), dim3(512), 0, stream>>>(captions, emb, Erow);
  k_init<<<dim3(64), dim3(512), 0, stream>>>(enc, W_hi, b_hi, W_ci, b_ci, hb0, cb0);

  // att1R = enc @ W_ea + b_ea  (row-major [b*196+l][512])
  k_gemm<<<dim3(8, 196), dim3(256), 0, stream>>>(enc_bf, WeaT, 512, 0, 512,
      b_ea, nullptr, nullptr, nullptr, att1R, nullptr);
  // preIHb[b][t][n] = emb_t @ W_ih_top
  k_gemm<<<dim3(32, 31), dim3(256), 0, stream>>>(Erow, WtopT, 512, 3, 2048,
      nullptr, nullptr, nullptr, nullptr, preIHb, nullptr);

  // ---- the whole 31-step recurrence: 64 independent blocks, zero grid syncs ----
  k_loop<<<dim3(64), dim3(1024), 0, stream>>>(W1p, W2p, preIHb, att1R, enc_bf,
      w_fa, b_da, b_fb, b_ih, b_hh, hb0, cb0, HZ, caplen, out + PRED_);

  // U = Erow + HZ @ [W_lh; W_lz] + b_lh + b_lz
  k_gemm<<<dim3(8, 31), dim3(256), 0, stream>>>(HZ, W2T, 1024, 1, 512,
      b_lh, b_lz, Erow, nullptr, Ubf, nullptr);
  // logits = U @ W_lo + b_lo (masked), 1-D XCD-swizzled grid of 157*31 tiles
  k_gemm<<<dim3(4867), dim3(256), 0, stream>>>(Ubf, WloT, 512, 2, 10000,
      b_lo, nullptr, nullptr, caplen, nullptr, out);
}